// Round 1
// baseline (1505.674 us; speedup 1.0000x reference)
//
#include <hip/hip_runtime.h>
#include <hip/hip_bf16.h>

// Problem constants
// B=512, N(L)=256, D=128, DI=256, NL=4, NS=16, KC=4, DH=64, H=64
// M = B*N = 131072 tokens

typedef __bf16 bf16_8 __attribute__((ext_vector_type(8)));
typedef float  f32_4  __attribute__((ext_vector_type(4)));

#define LDKC 72   // 64 K-chunk + 8 pad (row stride 144B, multiple of 16B)

// ---------------------------------------------------------------------------
// prep: convert W_in (4*512*128) and W_out (4*128*256) fp32 -> bf16
__global__ __launch_bounds__(256) void prep_kernel(const float* __restrict__ win,
                                                   const float* __restrict__ wout,
                                                   __bf16* __restrict__ win16,
                                                   __bf16* __restrict__ wout16) {
    int i = blockIdx.x * 256 + threadIdx.x;
    if (i < 4 * 512 * 128) win16[i] = (__bf16)win[i];
    if (i < 4 * 128 * 256) wout16[i] = (__bf16)wout[i];
}

// ---------------------------------------------------------------------------
// x = init + pos (broadcast over batch)
__global__ __launch_bounds__(256) void add_pos_kernel(const float4* __restrict__ a,
                                                      const float4* __restrict__ p,
                                                      float4* __restrict__ x) {
    int i = blockIdx.x * 256 + threadIdx.x;       // 4194304 total float4
    float4 u = a[i];
    float4 v = p[i & 8191];                       // N*D/4 = 8192 per batch
    x[i] = make_float4(u.x + v.x, u.y + v.y, u.z + v.z, u.w + v.w);
}

// ---------------------------------------------------------------------------
// LayerNorm: x fp32 -> h bf16.  One wave per token (D=128, 2 elems/lane).
__global__ __launch_bounds__(256) void ln_kernel(const float* __restrict__ x,
                                                 const float* __restrict__ g,
                                                 const float* __restrict__ bta,
                                                 __bf16* __restrict__ h) {
    int wave = threadIdx.x >> 6, lane = threadIdx.x & 63;
    long tok = (long)blockIdx.x * 4 + wave;
    const float* xr = x + tok * 128;
    float v0 = xr[lane], v1 = xr[lane + 64];
    float s = v0 + v1, ss = v0 * v0 + v1 * v1;
    #pragma unroll
    for (int o = 32; o; o >>= 1) { s += __shfl_xor(s, o); ss += __shfl_xor(ss, o); }
    float m = s * (1.0f / 128.0f);
    float var = ss * (1.0f / 128.0f) - m * m;
    float r = rsqrtf(var + 1e-5f);
    __bf16* hr = h + tok * 128;
    hr[lane]      = (__bf16)((v0 - m) * r * g[lane]      + bta[lane]);
    hr[lane + 64] = (__bf16)((v1 - m) * r * g[lane + 64] + bta[lane + 64]);
}

// ---------------------------------------------------------------------------
// GEMM1: xz[m,n] = sum_k h[m,k] * Win[n,k]; M=131072, N=512, K=128.
// Block tile 128x128, 4 waves in 2x2, each wave 64x64 via 4x4 16x16x32 MFMA.
// K chunked at 64 to fit LDS under 64KB.
__global__ __launch_bounds__(256) void gemm1_kernel(const __bf16* __restrict__ hmat,
                                                    const __bf16* __restrict__ win,
                                                    __bf16* __restrict__ xp,
                                                    __bf16* __restrict__ z) {
    __shared__ __bf16 As[128 * LDKC];
    __shared__ __bf16 Bs[128 * LDKC];
    int tid = threadIdx.x;
    long m0 = (long)blockIdx.x * 128;
    int n0 = blockIdx.y * 128;
    int wave = tid >> 6, lane = tid & 63;
    int wm = wave >> 1, wn = wave & 1;
    int lrow = lane & 15, lk = (lane >> 4) * 8;
    f32_4 acc[4][4] = {};

    for (int kc = 0; kc < 2; ++kc) {
        // A: h rows m0..+127, k in [kc*64, kc*64+64)
        const __bf16* asrc = hmat + m0 * 128 + kc * 64;
        const __bf16* bsrc = win + (long)n0 * 128 + kc * 64;
        #pragma unroll
        for (int i = 0; i < 4; ++i) {
            int idx = tid + i * 256;          // 0..1023
            int row = idx >> 3, c4 = idx & 7; // 8 uint4 per 64-elem row
            uint4 va = *(const uint4*)(asrc + row * 128 + c4 * 8);
            *(uint4*)(As + row * LDKC + c4 * 8) = va;
            uint4 vb = *(const uint4*)(bsrc + row * 128 + c4 * 8);
            *(uint4*)(Bs + row * LDKC + c4 * 8) = vb;
        }
        __syncthreads();
        #pragma unroll
        for (int kk = 0; kk < 64; kk += 32) {
            bf16_8 a[4], b[4];
            #pragma unroll
            for (int mt = 0; mt < 4; ++mt)
                a[mt] = *(const bf16_8*)(As + (wm * 64 + mt * 16 + lrow) * LDKC + kk + lk);
            #pragma unroll
            for (int nt = 0; nt < 4; ++nt)
                b[nt] = *(const bf16_8*)(Bs + (wn * 64 + nt * 16 + lrow) * LDKC + kk + lk);
            #pragma unroll
            for (int mt = 0; mt < 4; ++mt)
                #pragma unroll
                for (int nt = 0; nt < 4; ++nt)
                    acc[mt][nt] = __builtin_amdgcn_mfma_f32_16x16x32_bf16(
                        a[mt], b[nt], acc[mt][nt], 0, 0, 0);
        }
        __syncthreads();
    }

    // Epilogue: write xp (n<256) or z (n>=256) as bf16
    bool isz = (n0 >= 256);
    __bf16* dst = isz ? z : xp;
    int ncol0 = isz ? n0 - 256 : n0;
    int row_base = (lane >> 4) * 4;
    int col = lane & 15;
    #pragma unroll
    for (int mt = 0; mt < 4; ++mt) {
        long mg = m0 + wm * 64 + mt * 16 + row_base;
        #pragma unroll
        for (int nt = 0; nt < 4; ++nt) {
            int ng = ncol0 + wn * 64 + nt * 16 + col;
            #pragma unroll
            for (int r = 0; r < 4; ++r)
                dst[(mg + r) * 256 + ng] = (__bf16)acc[mt][nt][r];
        }
    }
}

// ---------------------------------------------------------------------------
// Fused depthwise causal conv(K=4) + S4D recurrence (n=16) + sigmoid gate.
// One thread per (b, channel); y written in place over xp.
__global__ __launch_bounds__(256) void conv_ssm_kernel(__bf16* __restrict__ xp_y,
                                                       const __bf16* __restrict__ z,
                                                       const float* __restrict__ cw,
                                                       const float* __restrict__ cb,
                                                       const float* __restrict__ Bp,
                                                       const float* __restrict__ Cp,
                                                       const float* __restrict__ ldt,
                                                       const float* __restrict__ Dp_p) {
    int b = blockIdx.x, c = threadIdx.x;
    float w0 = cw[c * 4 + 0], w1 = cw[c * 4 + 1], w2 = cw[c * 4 + 2], w3 = cw[c * 4 + 3];
    float bias = cb[c];
    float dt = expf(ldt[0]);
    dt = fminf(fmaxf(dt, 1e-4f), 1.0f);
    float Dp = Dp_p[0];
    float dA[16], CdB[16], s[16];
    #pragma unroll
    for (int n = 0; n < 16; ++n) {
        float A = -(float)(n + 1);
        float da = expf(fminf(fmaxf(dt * A, -10.0f), 10.0f));
        float dB = (da - 1.0f) / A * Bp[n];
        dA[n] = da;
        CdB[n] = Cp[n] * dB;
        s[n] = 0.0f;
    }
    float u1 = 0.0f, u2 = 0.0f, u3 = 0.0f;   // x[l-1], x[l-2], x[l-3]
    __bf16* xrow = xp_y + (long)b * 256 * 256 + c;
    const __bf16* zrow = z + (long)b * 256 * 256 + c;
    #pragma unroll 4
    for (int l = 0; l < 256; ++l) {
        float xv = (float)xrow[l * 256];
        float u = bias + w0 * u3 + w1 * u2 + w2 * u1 + w3 * xv;  // conv output
        u3 = u2; u2 = u1; u1 = xv;
        float acc = Dp * u;
        #pragma unroll
        for (int n = 0; n < 16; ++n) {
            s[n] = s[n] * dA[n] + u;
            acc += CdB[n] * s[n];
        }
        float zv = (float)zrow[l * 256];
        float gate = 1.0f / (1.0f + expf(-zv));
        xrow[l * 256] = (__bf16)(acc * gate);
    }
}

// ---------------------------------------------------------------------------
// GEMM2 + residual: x[m,d] += clip(rs)*sum_c y[m,c]*Wout[d,c]; M=131072,N=128,K=256
__global__ __launch_bounds__(256) void gemm2_kernel(const __bf16* __restrict__ y,
                                                    const __bf16* __restrict__ wout,
                                                    float* __restrict__ x,
                                                    const float* __restrict__ rs_p) {
    __shared__ __bf16 As[128 * LDKC];
    __shared__ __bf16 Bs[128 * LDKC];
    int tid = threadIdx.x;
    long m0 = (long)blockIdx.x * 128;
    int wave = tid >> 6, lane = tid & 63;
    int wm = wave >> 1, wn = wave & 1;
    int lrow = lane & 15, lk = (lane >> 4) * 8;
    f32_4 acc[4][4] = {};

    for (int kc = 0; kc < 4; ++kc) {
        const __bf16* asrc = y + m0 * 256 + kc * 64;
        const __bf16* bsrc = wout + kc * 64;
        #pragma unroll
        for (int i = 0; i < 4; ++i) {
            int idx = tid + i * 256;
            int row = idx >> 3, c4 = idx & 7;
            uint4 va = *(const uint4*)(asrc + row * 256 + c4 * 8);
            *(uint4*)(As + row * LDKC + c4 * 8) = va;
            uint4 vb = *(const uint4*)(bsrc + row * 256 + c4 * 8);
            *(uint4*)(Bs + row * LDKC + c4 * 8) = vb;
        }
        __syncthreads();
        #pragma unroll
        for (int kk = 0; kk < 64; kk += 32) {
            bf16_8 a[4], b[4];
            #pragma unroll
            for (int mt = 0; mt < 4; ++mt)
                a[mt] = *(const bf16_8*)(As + (wm * 64 + mt * 16 + lrow) * LDKC + kk + lk);
            #pragma unroll
            for (int nt = 0; nt < 4; ++nt)
                b[nt] = *(const bf16_8*)(Bs + (wn * 64 + nt * 16 + lrow) * LDKC + kk + lk);
            #pragma unroll
            for (int mt = 0; mt < 4; ++mt)
                #pragma unroll
                for (int nt = 0; nt < 4; ++nt)
                    acc[mt][nt] = __builtin_amdgcn_mfma_f32_16x16x32_bf16(
                        a[mt], b[nt], acc[mt][nt], 0, 0, 0);
        }
        __syncthreads();
    }

    float rs = rs_p[0];
    rs = fminf(fmaxf(rs, 0.0f), 1.5f);
    int row_base = (lane >> 4) * 4;
    int col = lane & 15;
    #pragma unroll
    for (int mt = 0; mt < 4; ++mt) {
        long mg = m0 + wm * 64 + mt * 16 + row_base;
        #pragma unroll
        for (int nt = 0; nt < 4; ++nt) {
            int d = wn * 64 + nt * 16 + col;
            #pragma unroll
            for (int r = 0; r < 4; ++r) {
                long idx = (mg + r) * 128 + d;
                x[idx] = x[idx] + rs * acc[mt][nt][r];
            }
        }
    }
}

// ---------------------------------------------------------------------------
// Final LN -> tokens (fp32 out), L2-normalize, MLP (gelu exact) -> logits
__global__ __launch_bounds__(256) void final_kernel(const float* __restrict__ x,
                                                    const float* __restrict__ fg,
                                                    const float* __restrict__ fb,
                                                    const float* __restrict__ W1,
                                                    const float* __restrict__ b1,
                                                    const float* __restrict__ W2,
                                                    const float* __restrict__ b2,
                                                    float* __restrict__ tokens,
                                                    float* __restrict__ logits) {
    __shared__ float tn_s[4][128];
    int wave = threadIdx.x >> 6, lane = threadIdx.x & 63;
    long tok = (long)blockIdx.x * 4 + wave;
    const float* xr = x + tok * 128;
    float v0 = xr[lane], v1 = xr[lane + 64];
    float s = v0 + v1, ss = v0 * v0 + v1 * v1;
    #pragma unroll
    for (int o = 32; o; o >>= 1) { s += __shfl_xor(s, o); ss += __shfl_xor(ss, o); }
    float m = s * (1.0f / 128.0f);
    float var = ss * (1.0f / 128.0f) - m * m;
    float r = rsqrtf(var + 1e-5f);
    float t0 = (v0 - m) * r * fg[lane]      + fb[lane];
    float t1 = (v1 - m) * r * fg[lane + 64] + fb[lane + 64];
    tokens[tok * 128 + lane]      = t0;
    tokens[tok * 128 + lane + 64] = t1;
    float q = t0 * t0 + t1 * t1;
    #pragma unroll
    for (int o = 32; o; o >>= 1) q += __shfl_xor(q, o);
    float inv = 1.0f / fmaxf(sqrtf(q), 1e-6f);
    tn_s[wave][lane]      = t0 * inv;
    tn_s[wave][lane + 64] = t1 * inv;
    __syncthreads();
    // h1[j] for j = lane (H=64), then logits = sum_j gelu(h1[j])*W2[j] + b2
    const float* w1r = W1 + lane * 128;
    float a = 0.0f;
    #pragma unroll 8
    for (int k = 0; k < 128; ++k) a += tn_s[wave][k] * w1r[k];
    a += b1[lane];
    float gl = 0.5f * a * (1.0f + erff(a * 0.70710678118654752f));  // exact gelu
    float p = gl * W2[lane];
    #pragma unroll
    for (int o = 32; o; o >>= 1) p += __shfl_xor(p, o);
    if (lane == 0) logits[tok] = p + b2[0];
}

// ---------------------------------------------------------------------------
// Per-batch softmax over L, feats = sum_l w_l * tokens, 3 small head linears
__global__ __launch_bounds__(256) void head_kernel(const float* __restrict__ tokens,
                                                   const float* __restrict__ logits,
                                                   const float* __restrict__ texW,
                                                   const float* __restrict__ texb,
                                                   const float* __restrict__ edgeW,
                                                   const float* __restrict__ edgeb,
                                                   const float* __restrict__ strW,
                                                   const float* __restrict__ strb,
                                                   float* __restrict__ feats_out,
                                                   float* __restrict__ tex_out,
                                                   float* __restrict__ edge_out,
                                                   float* __restrict__ str_out,
                                                   float* __restrict__ w_out) {
    __shared__ float wsm[256];
    __shared__ float red[8];
    __shared__ float feats_s[128];
    int b = blockIdx.x, tid = threadIdx.x;
    int lane = tid & 63, wave = tid >> 6;
    float lg = logits[(long)b * 256 + tid];
    float mx = lg;
    #pragma unroll
    for (int o = 32; o; o >>= 1) mx = fmaxf(mx, __shfl_xor(mx, o));
    if (lane == 0) red[wave] = mx;
    __syncthreads();
    float bm = fmaxf(fmaxf(red[0], red[1]), fmaxf(red[2], red[3]));
    float e = expf(lg - bm);
    float se = e;
    #pragma unroll
    for (int o = 32; o; o >>= 1) se += __shfl_xor(se, o);
    if (lane == 0) red[4 + wave] = se;
    __syncthreads();
    float tot = red[4] + red[5] + red[6] + red[7];
    float w = e / tot;
    wsm[tid] = w;
    w_out[(long)b * 256 + tid] = w;
    __syncthreads();
    if (tid < 128) {
        float acc = 0.0f;
        const float* tb = tokens + (long)b * 256 * 128 + tid;
        #pragma unroll 4
        for (int l = 0; l < 256; ++l) acc += tb[l * 128] * wsm[l];
        feats_s[tid] = acc;
        feats_out[(long)b * 128 + tid] = acc;
    }
    __syncthreads();
    if (tid < 192) {
        int head = tid >> 6, j = tid & 63;
        const float* W  = head == 0 ? texW : (head == 1 ? edgeW : strW);
        const float* bi = head == 0 ? texb : (head == 1 ? edgeb : strb);
        float* outp     = head == 0 ? tex_out : (head == 1 ? edge_out : str_out);
        const float* wr = W + j * 128;
        float acc = 0.0f;
        #pragma unroll 8
        for (int k = 0; k < 128; ++k) acc += feats_s[k] * wr[k];
        outp[(long)b * 64 + j] = acc + bi[j];
    }
}

// ---------------------------------------------------------------------------
extern "C" void kernel_launch(void* const* d_in, const int* in_sizes, int n_in,
                              void* d_out, int out_size, void* d_ws, size_t ws_size,
                              hipStream_t stream) {
    const float* init   = (const float*)d_in[0];
    const float* pos    = (const float*)d_in[1];
    const float* ln_g   = (const float*)d_in[2];
    const float* ln_b   = (const float*)d_in[3];
    const float* W_in   = (const float*)d_in[4];
    const float* conv_w = (const float*)d_in[5];
    const float* conv_b = (const float*)d_in[6];
    const float* ssm_B  = (const float*)d_in[7];
    const float* ssm_C  = (const float*)d_in[8];
    const float* log_dt = (const float*)d_in[9];
    const float* ssm_D  = (const float*)d_in[10];
    const float* W_out  = (const float*)d_in[11];
    const float* res_sc = (const float*)d_in[12];
    const float* fin_g  = (const float*)d_in[13];
    const float* fin_b  = (const float*)d_in[14];
    const float* imp_W1 = (const float*)d_in[15];
    const float* imp_b1 = (const float*)d_in[16];
    const float* imp_W2 = (const float*)d_in[17];
    const float* imp_b2 = (const float*)d_in[18];
    const float* tex_W  = (const float*)d_in[19];
    const float* tex_b  = (const float*)d_in[20];
    const float* edge_W = (const float*)d_in[21];
    const float* edge_b = (const float*)d_in[22];
    const float* str_W  = (const float*)d_in[23];
    const float* str_b  = (const float*)d_in[24];

    float* out = (float*)d_out;
    char* ws = (char*)d_ws;
    float*  x      = (float*)ws;                      // 67108864 B  (M*D fp32)
    __bf16* xpb    = (__bf16*)(ws + 67108864);        // 67108864 B  (M*DI bf16; y in place)
    __bf16* zb     = (__bf16*)(ws + 134217728);       // 67108864 B
    __bf16* hb     = (__bf16*)(ws + 201326592);       // 33554432 B  (M*D bf16)
    __bf16* win16  = (__bf16*)(ws + 234881024);       // 524288 B
    __bf16* wout16 = (__bf16*)(ws + 235405312);       // 262144 B
    float*  logits = (float*)(ws + 235667456);        // 524288 B

    prep_kernel<<<1024, 256, 0, stream>>>(W_in, W_out, win16, wout16);
    add_pos_kernel<<<16384, 256, 0, stream>>>((const float4*)init, (const float4*)pos,
                                              (float4*)x);
    for (int l = 0; l < 4; ++l) {
        ln_kernel<<<32768, 256, 0, stream>>>(x, ln_g + l * 128, ln_b + l * 128, hb);
        gemm1_kernel<<<dim3(1024, 4), 256, 0, stream>>>(hb, win16 + l * 65536, xpb, zb);
        conv_ssm_kernel<<<512, 256, 0, stream>>>(xpb, zb, conv_w + l * 1024,
                                                 conv_b + l * 256, ssm_B + l * 16,
                                                 ssm_C + l * 16, log_dt + l, ssm_D + l);
        gemm2_kernel<<<1024, 256, 0, stream>>>(xpb, wout16 + l * 32768, x, res_sc + l);
    }
    float* tokens = out + 163840;
    final_kernel<<<32768, 256, 0, stream>>>(x, fin_g, fin_b, imp_W1, imp_b1,
                                            imp_W2, imp_b2, tokens, logits);
    head_kernel<<<512, 256, 0, stream>>>(tokens, logits, tex_W, tex_b, edge_W, edge_b,
                                         str_W, str_b, out, out + 65536, out + 98304,
                                         out + 131072, out + 16941056);
}

// Round 2
// 1095.307 us; speedup vs baseline: 1.3747x; 1.3747x over previous
//
#include <hip/hip_runtime.h>
#include <hip/hip_bf16.h>

// Problem constants
// B=512, N(L)=256, D=128, DI=256, NL=4, NS=16, KC=4, DH=64, H=64
// M = B*N = 131072 tokens

typedef __bf16 bf16_8 __attribute__((ext_vector_type(8)));
typedef float  f32_4  __attribute__((ext_vector_type(4)));

#define LDKC 72   // 64 K-chunk + 8 pad (row stride 144B, multiple of 16B)

// ---------------------------------------------------------------------------
// prep: convert W_in (4*512*128), W_out (4*128*256), imp_W1 (64*128) fp32->bf16
__global__ __launch_bounds__(256) void prep_kernel(const float* __restrict__ win,
                                                   const float* __restrict__ wout,
                                                   const float* __restrict__ w1,
                                                   __bf16* __restrict__ win16,
                                                   __bf16* __restrict__ wout16,
                                                   __bf16* __restrict__ w116) {
    int i = blockIdx.x * 256 + threadIdx.x;
    if (i < 4 * 512 * 128) win16[i] = (__bf16)win[i];
    if (i < 4 * 128 * 256) wout16[i] = (__bf16)wout[i];
    if (i < 64 * 128)      w116[i]  = (__bf16)w1[i];
}

// ---------------------------------------------------------------------------
// x = init + pos (broadcast over batch)
__global__ __launch_bounds__(256) void add_pos_kernel(const float4* __restrict__ a,
                                                      const float4* __restrict__ p,
                                                      float4* __restrict__ x) {
    int i = blockIdx.x * 256 + threadIdx.x;       // 4194304 total float4
    float4 u = a[i];
    float4 v = p[i & 8191];                       // N*D/4 = 8192 per batch
    x[i] = make_float4(u.x + v.x, u.y + v.y, u.z + v.z, u.w + v.w);
}

// ---------------------------------------------------------------------------
// LayerNorm: x fp32 -> h bf16.  One wave per token (D=128, 2 elems/lane).
__global__ __launch_bounds__(256) void ln_kernel(const float* __restrict__ x,
                                                 const float* __restrict__ g,
                                                 const float* __restrict__ bta,
                                                 __bf16* __restrict__ h) {
    int wave = threadIdx.x >> 6, lane = threadIdx.x & 63;
    long tok = (long)blockIdx.x * 4 + wave;
    const float* xr = x + tok * 128;
    float v0 = xr[lane], v1 = xr[lane + 64];
    float s = v0 + v1, ss = v0 * v0 + v1 * v1;
    #pragma unroll
    for (int o = 32; o; o >>= 1) { s += __shfl_xor(s, o); ss += __shfl_xor(ss, o); }
    float m = s * (1.0f / 128.0f);
    float var = ss * (1.0f / 128.0f) - m * m;
    float r = rsqrtf(var + 1e-5f);
    __bf16* hr = h + tok * 128;
    hr[lane]      = (__bf16)((v0 - m) * r * g[lane]      + bta[lane]);
    hr[lane + 64] = (__bf16)((v1 - m) * r * g[lane + 64] + bta[lane + 64]);
}

// ---------------------------------------------------------------------------
// GEMM1: xz[m,n] = sum_k h[m,k] * Win[n,k]; M=131072, N=512, K=128.
__global__ __launch_bounds__(256) void gemm1_kernel(const __bf16* __restrict__ hmat,
                                                    const __bf16* __restrict__ win,
                                                    __bf16* __restrict__ xp,
                                                    __bf16* __restrict__ z) {
    __shared__ __bf16 As[128 * LDKC];
    __shared__ __bf16 Bs[128 * LDKC];
    int tid = threadIdx.x;
    long m0 = (long)blockIdx.x * 128;
    int n0 = blockIdx.y * 128;
    int wave = tid >> 6, lane = tid & 63;
    int wm = wave >> 1, wn = wave & 1;
    int lrow = lane & 15, lk = (lane >> 4) * 8;
    f32_4 acc[4][4] = {};

    for (int kc = 0; kc < 2; ++kc) {
        const __bf16* asrc = hmat + m0 * 128 + kc * 64;
        const __bf16* bsrc = win + (long)n0 * 128 + kc * 64;
        #pragma unroll
        for (int i = 0; i < 4; ++i) {
            int idx = tid + i * 256;          // 0..1023
            int row = idx >> 3, c4 = idx & 7; // 8 uint4 per 64-elem row
            uint4 va = *(const uint4*)(asrc + row * 128 + c4 * 8);
            *(uint4*)(As + row * LDKC + c4 * 8) = va;
            uint4 vb = *(const uint4*)(bsrc + row * 128 + c4 * 8);
            *(uint4*)(Bs + row * LDKC + c4 * 8) = vb;
        }
        __syncthreads();
        #pragma unroll
        for (int kk = 0; kk < 64; kk += 32) {
            bf16_8 a[4], b[4];
            #pragma unroll
            for (int mt = 0; mt < 4; ++mt)
                a[mt] = *(const bf16_8*)(As + (wm * 64 + mt * 16 + lrow) * LDKC + kk + lk);
            #pragma unroll
            for (int nt = 0; nt < 4; ++nt)
                b[nt] = *(const bf16_8*)(Bs + (wn * 64 + nt * 16 + lrow) * LDKC + kk + lk);
            #pragma unroll
            for (int mt = 0; mt < 4; ++mt)
                #pragma unroll
                for (int nt = 0; nt < 4; ++nt)
                    acc[mt][nt] = __builtin_amdgcn_mfma_f32_16x16x32_bf16(
                        a[mt], b[nt], acc[mt][nt], 0, 0, 0);
        }
        __syncthreads();
    }

    bool isz = (n0 >= 256);
    __bf16* dst = isz ? z : xp;
    int ncol0 = isz ? n0 - 256 : n0;
    int row_base = (lane >> 4) * 4;
    int col = lane & 15;
    #pragma unroll
    for (int mt = 0; mt < 4; ++mt) {
        long mg = m0 + wm * 64 + mt * 16 + row_base;
        #pragma unroll
        for (int nt = 0; nt < 4; ++nt) {
            int ng = ncol0 + wn * 64 + nt * 16 + col;
            #pragma unroll
            for (int r = 0; r < 4; ++r)
                dst[(mg + r) * 256 + ng] = (__bf16)acc[mt][nt][r];
        }
    }
}

// ---------------------------------------------------------------------------
// Fused depthwise causal conv(K=4) + S4D recurrence (n=16) + sigmoid gate.
__global__ __launch_bounds__(256) void conv_ssm_kernel(__bf16* __restrict__ xp_y,
                                                       const __bf16* __restrict__ z,
                                                       const float* __restrict__ cw,
                                                       const float* __restrict__ cb,
                                                       const float* __restrict__ Bp,
                                                       const float* __restrict__ Cp,
                                                       const float* __restrict__ ldt,
                                                       const float* __restrict__ Dp_p) {
    int b = blockIdx.x, c = threadIdx.x;
    float w0 = cw[c * 4 + 0], w1 = cw[c * 4 + 1], w2 = cw[c * 4 + 2], w3 = cw[c * 4 + 3];
    float bias = cb[c];
    float dt = expf(ldt[0]);
    dt = fminf(fmaxf(dt, 1e-4f), 1.0f);
    float Dp = Dp_p[0];
    float dA[16], CdB[16], s[16];
    #pragma unroll
    for (int n = 0; n < 16; ++n) {
        float A = -(float)(n + 1);
        float da = expf(fminf(fmaxf(dt * A, -10.0f), 10.0f));
        float dB = (da - 1.0f) / A * Bp[n];
        dA[n] = da;
        CdB[n] = Cp[n] * dB;
        s[n] = 0.0f;
    }
    float u1 = 0.0f, u2 = 0.0f, u3 = 0.0f;
    __bf16* xrow = xp_y + (long)b * 256 * 256 + c;
    const __bf16* zrow = z + (long)b * 256 * 256 + c;
    #pragma unroll 4
    for (int l = 0; l < 256; ++l) {
        float xv = (float)xrow[l * 256];
        float u = bias + w0 * u3 + w1 * u2 + w2 * u1 + w3 * xv;
        u3 = u2; u2 = u1; u1 = xv;
        float acc = Dp * u;
        #pragma unroll
        for (int n = 0; n < 16; ++n) {
            s[n] = s[n] * dA[n] + u;
            acc += CdB[n] * s[n];
        }
        float zv = (float)zrow[l * 256];
        float gate = 1.0f / (1.0f + expf(-zv));
        xrow[l * 256] = (__bf16)(acc * gate);
    }
}

// ---------------------------------------------------------------------------
// GEMM2 + residual: x[m,d] += clip(rs)*sum_c y[m,c]*Wout[d,c]; M=131072,N=128,K=256
__global__ __launch_bounds__(256) void gemm2_kernel(const __bf16* __restrict__ y,
                                                    const __bf16* __restrict__ wout,
                                                    float* __restrict__ x,
                                                    const float* __restrict__ rs_p) {
    __shared__ __bf16 As[128 * LDKC];
    __shared__ __bf16 Bs[128 * LDKC];
    int tid = threadIdx.x;
    long m0 = (long)blockIdx.x * 128;
    int wave = tid >> 6, lane = tid & 63;
    int wm = wave >> 1, wn = wave & 1;
    int lrow = lane & 15, lk = (lane >> 4) * 8;
    f32_4 acc[4][4] = {};

    for (int kc = 0; kc < 4; ++kc) {
        const __bf16* asrc = y + m0 * 256 + kc * 64;
        const __bf16* bsrc = wout + kc * 64;
        #pragma unroll
        for (int i = 0; i < 4; ++i) {
            int idx = tid + i * 256;
            int row = idx >> 3, c4 = idx & 7;
            uint4 va = *(const uint4*)(asrc + row * 256 + c4 * 8);
            *(uint4*)(As + row * LDKC + c4 * 8) = va;
            uint4 vb = *(const uint4*)(bsrc + row * 256 + c4 * 8);
            *(uint4*)(Bs + row * LDKC + c4 * 8) = vb;
        }
        __syncthreads();
        #pragma unroll
        for (int kk = 0; kk < 64; kk += 32) {
            bf16_8 a[4], b[4];
            #pragma unroll
            for (int mt = 0; mt < 4; ++mt)
                a[mt] = *(const bf16_8*)(As + (wm * 64 + mt * 16 + lrow) * LDKC + kk + lk);
            #pragma unroll
            for (int nt = 0; nt < 4; ++nt)
                b[nt] = *(const bf16_8*)(Bs + (wn * 64 + nt * 16 + lrow) * LDKC + kk + lk);
            #pragma unroll
            for (int mt = 0; mt < 4; ++mt)
                #pragma unroll
                for (int nt = 0; nt < 4; ++nt)
                    acc[mt][nt] = __builtin_amdgcn_mfma_f32_16x16x32_bf16(
                        a[mt], b[nt], acc[mt][nt], 0, 0, 0);
        }
        __syncthreads();
    }

    float rs = rs_p[0];
    rs = fminf(fmaxf(rs, 0.0f), 1.5f);
    int row_base = (lane >> 4) * 4;
    int col = lane & 15;
    #pragma unroll
    for (int mt = 0; mt < 4; ++mt) {
        long mg = m0 + wm * 64 + mt * 16 + row_base;
        #pragma unroll
        for (int nt = 0; nt < 4; ++nt) {
            int d = wn * 64 + nt * 16 + col;
            #pragma unroll
            for (int r = 0; r < 4; ++r) {
                long idx = (mg + r) * 128 + d;
                x[idx] = x[idx] + rs * acc[mt][nt][r];
            }
        }
    }
}

// ---------------------------------------------------------------------------
// Final LN -> tokens (fp32 output) + L2-normalized tn (bf16, workspace)
__global__ __launch_bounds__(256) void ln_final_kernel(const float* __restrict__ x,
                                                       const float* __restrict__ fg,
                                                       const float* __restrict__ fb,
                                                       float* __restrict__ tokens,
                                                       __bf16* __restrict__ tn) {
    int wave = threadIdx.x >> 6, lane = threadIdx.x & 63;
    long tok = (long)blockIdx.x * 4 + wave;
    const float* xr = x + tok * 128;
    float v0 = xr[lane], v1 = xr[lane + 64];
    float s = v0 + v1, ss = v0 * v0 + v1 * v1;
    #pragma unroll
    for (int o = 32; o; o >>= 1) { s += __shfl_xor(s, o); ss += __shfl_xor(ss, o); }
    float m = s * (1.0f / 128.0f);
    float var = ss * (1.0f / 128.0f) - m * m;
    float r = rsqrtf(var + 1e-5f);
    float t0 = (v0 - m) * r * fg[lane]      + fb[lane];
    float t1 = (v1 - m) * r * fg[lane + 64] + fb[lane + 64];
    tokens[tok * 128 + lane]      = t0;
    tokens[tok * 128 + lane + 64] = t1;
    float q = t0 * t0 + t1 * t1;
    #pragma unroll
    for (int o = 32; o; o >>= 1) q += __shfl_xor(q, o);
    float inv = 1.0f / fmaxf(sqrtf(q), 1e-6f);
    tn[tok * 128 + lane]      = (__bf16)(t0 * inv);
    tn[tok * 128 + lane + 64] = (__bf16)(t1 * inv);
}

// ---------------------------------------------------------------------------
// MLP via MFMA: logits[m] = gelu(tn[m,:] @ W1.T + b1) @ W2 + b2
// M=131072, N=64, K=128. Block: 128 tokens, 4 waves x 32 tokens.
#define LDA 136   // 128 + 8 pad (bf16 elems), row stride 272 B
__global__ __launch_bounds__(256) void mlp_kernel(const __bf16* __restrict__ tn,
                                                  const __bf16* __restrict__ w1b,
                                                  const float* __restrict__ b1,
                                                  const float* __restrict__ W2,
                                                  const float* __restrict__ b2,
                                                  float* __restrict__ logits) {
    __shared__ __bf16 As[128 * LDA];   // 34816 B
    __shared__ __bf16 Bs[64 * LDA];    // 17408 B
    int tid = threadIdx.x;
    long m0 = (long)blockIdx.x * 128;
    // stage A: 128x128 bf16 = 2048 uint4
    const __bf16* asrc = tn + m0 * 128;
    #pragma unroll
    for (int i = 0; i < 8; ++i) {
        int idx = tid + i * 256;           // 0..2047
        int row = idx >> 4, c = idx & 15;  // 16 uint4 per row
        uint4 v = *(const uint4*)(asrc + row * 128 + c * 8);
        *(uint4*)(As + row * LDA + c * 8) = v;
    }
    // stage B (W1): 64x128 bf16 = 1024 uint4
    #pragma unroll
    for (int i = 0; i < 4; ++i) {
        int idx = tid + i * 256;
        int row = idx >> 4, c = idx & 15;
        uint4 v = *(const uint4*)(w1b + row * 128 + c * 8);
        *(uint4*)(Bs + row * LDA + c * 8) = v;
    }
    __syncthreads();

    int wave = tid >> 6, lane = tid & 63;
    int lrow = lane & 15, lk = (lane >> 4) * 8;
    f32_4 acc[2][4] = {};
    #pragma unroll
    for (int kk = 0; kk < 128; kk += 32) {
        bf16_8 a[2], b[4];
        #pragma unroll
        for (int mt = 0; mt < 2; ++mt)
            a[mt] = *(const bf16_8*)(As + (wave * 32 + mt * 16 + lrow) * LDA + kk + lk);
        #pragma unroll
        for (int nt = 0; nt < 4; ++nt)
            b[nt] = *(const bf16_8*)(Bs + (nt * 16 + lrow) * LDA + kk + lk);
        #pragma unroll
        for (int mt = 0; mt < 2; ++mt)
            #pragma unroll
            for (int nt = 0; nt < 4; ++nt)
                acc[mt][nt] = __builtin_amdgcn_mfma_f32_16x16x32_bf16(
                    a[mt], b[nt], acc[mt][nt], 0, 0, 0);
    }

    // epilogue: h = acc + b1; gelu; dot with W2 over j; reduce across 16 lanes
    int col = lane & 15, quad = lane >> 4;
    float b2v = b2[0];
    #pragma unroll
    for (int mt = 0; mt < 2; ++mt) {
        #pragma unroll
        for (int r = 0; r < 4; ++r) {
            float p = 0.0f;
            #pragma unroll
            for (int nt = 0; nt < 4; ++nt) {
                int j = nt * 16 + col;
                float a = acc[mt][nt][r] + b1[j];
                float gl = 0.5f * a * (1.0f + erff(a * 0.70710678118654752f));
                p += gl * W2[j];
            }
            #pragma unroll
            for (int o = 8; o; o >>= 1) p += __shfl_xor(p, o);
            if (col == 0) {
                long tok = m0 + wave * 32 + mt * 16 + quad * 4 + r;
                logits[tok] = p + b2v;
            }
        }
    }
}

// ---------------------------------------------------------------------------
// Per-batch softmax over L, feats = sum_l w_l * tokens, 3 small head linears
__global__ __launch_bounds__(256) void head_kernel(const float* __restrict__ tokens,
                                                   const float* __restrict__ logits,
                                                   const float* __restrict__ texW,
                                                   const float* __restrict__ texb,
                                                   const float* __restrict__ edgeW,
                                                   const float* __restrict__ edgeb,
                                                   const float* __restrict__ strW,
                                                   const float* __restrict__ strb,
                                                   float* __restrict__ feats_out,
                                                   float* __restrict__ tex_out,
                                                   float* __restrict__ edge_out,
                                                   float* __restrict__ str_out,
                                                   float* __restrict__ w_out) {
    __shared__ float wsm[256];
    __shared__ float red[8];
    __shared__ float feats_s[128];
    int b = blockIdx.x, tid = threadIdx.x;
    int lane = tid & 63, wave = tid >> 6;
    float lg = logits[(long)b * 256 + tid];
    float mx = lg;
    #pragma unroll
    for (int o = 32; o; o >>= 1) mx = fmaxf(mx, __shfl_xor(mx, o));
    if (lane == 0) red[wave] = mx;
    __syncthreads();
    float bm = fmaxf(fmaxf(red[0], red[1]), fmaxf(red[2], red[3]));
    float e = expf(lg - bm);
    float se = e;
    #pragma unroll
    for (int o = 32; o; o >>= 1) se += __shfl_xor(se, o);
    if (lane == 0) red[4 + wave] = se;
    __syncthreads();
    float tot = red[4] + red[5] + red[6] + red[7];
    float w = e / tot;
    wsm[tid] = w;
    w_out[(long)b * 256 + tid] = w;
    __syncthreads();
    if (tid < 128) {
        float acc = 0.0f;
        const float* tb = tokens + (long)b * 256 * 128 + tid;
        #pragma unroll 4
        for (int l = 0; l < 256; ++l) acc += tb[l * 128] * wsm[l];
        feats_s[tid] = acc;
        feats_out[(long)b * 128 + tid] = acc;
    }
    __syncthreads();
    if (tid < 192) {
        int head = tid >> 6, j = tid & 63;
        const float* W  = head == 0 ? texW : (head == 1 ? edgeW : strW);
        const float* bi = head == 0 ? texb : (head == 1 ? edgeb : strb);
        float* outp     = head == 0 ? tex_out : (head == 1 ? edge_out : str_out);
        const float* wr = W + j * 128;
        float acc = 0.0f;
        #pragma unroll 8
        for (int k = 0; k < 128; ++k) acc += feats_s[k] * wr[k];
        outp[(long)b * 64 + j] = acc + bi[j];
    }
}

// ---------------------------------------------------------------------------
extern "C" void kernel_launch(void* const* d_in, const int* in_sizes, int n_in,
                              void* d_out, int out_size, void* d_ws, size_t ws_size,
                              hipStream_t stream) {
    const float* init   = (const float*)d_in[0];
    const float* pos    = (const float*)d_in[1];
    const float* ln_g   = (const float*)d_in[2];
    const float* ln_b   = (const float*)d_in[3];
    const float* W_in   = (const float*)d_in[4];
    const float* conv_w = (const float*)d_in[5];
    const float* conv_b = (const float*)d_in[6];
    const float* ssm_B  = (const float*)d_in[7];
    const float* ssm_C  = (const float*)d_in[8];
    const float* log_dt = (const float*)d_in[9];
    const float* ssm_D  = (const float*)d_in[10];
    const float* W_out  = (const float*)d_in[11];
    const float* res_sc = (const float*)d_in[12];
    const float* fin_g  = (const float*)d_in[13];
    const float* fin_b  = (const float*)d_in[14];
    const float* imp_W1 = (const float*)d_in[15];
    const float* imp_b1 = (const float*)d_in[16];
    const float* imp_W2 = (const float*)d_in[17];
    const float* imp_b2 = (const float*)d_in[18];
    const float* tex_W  = (const float*)d_in[19];
    const float* tex_b  = (const float*)d_in[20];
    const float* edge_W = (const float*)d_in[21];
    const float* edge_b = (const float*)d_in[22];
    const float* str_W  = (const float*)d_in[23];
    const float* str_b  = (const float*)d_in[24];

    float* out = (float*)d_out;
    char* ws = (char*)d_ws;
    float*  x      = (float*)ws;                      // 67108864 B  (M*D fp32)
    __bf16* xpb    = (__bf16*)(ws + 67108864);        // 67108864 B  (M*DI bf16; y in place)
    __bf16* zb     = (__bf16*)(ws + 134217728);       // 67108864 B
    __bf16* hb     = (__bf16*)(ws + 201326592);       // 33554432 B  (M*D bf16; reused as tn)
    __bf16* win16  = (__bf16*)(ws + 234881024);       // 524288 B
    __bf16* wout16 = (__bf16*)(ws + 235405312);       // 262144 B
    float*  logits = (float*)(ws + 235667456);        // 524288 B
    __bf16* w1b    = (__bf16*)(ws + 236191744);       // 16384 B

    prep_kernel<<<1024, 256, 0, stream>>>(W_in, W_out, imp_W1, win16, wout16, w1b);
    add_pos_kernel<<<16384, 256, 0, stream>>>((const float4*)init, (const float4*)pos,
                                              (float4*)x);
    for (int l = 0; l < 4; ++l) {
        ln_kernel<<<32768, 256, 0, stream>>>(x, ln_g + l * 128, ln_b + l * 128, hb);
        gemm1_kernel<<<dim3(1024, 4), 256, 0, stream>>>(hb, win16 + l * 65536, xpb, zb);
        conv_ssm_kernel<<<512, 256, 0, stream>>>(xpb, zb, conv_w + l * 1024,
                                                 conv_b + l * 256, ssm_B + l * 16,
                                                 ssm_C + l * 16, log_dt + l, ssm_D + l);
        gemm2_kernel<<<1024, 256, 0, stream>>>(xpb, wout16 + l * 32768, x, res_sc + l);
    }
    float* tokens = out + 163840;
    __bf16* tn = hb;  // reuse: hb is dead after the layer loop
    ln_final_kernel<<<32768, 256, 0, stream>>>(x, fin_g, fin_b, tokens, tn);
    mlp_kernel<<<1024, 256, 0, stream>>>(tn, w1b, imp_b1, imp_W2, imp_b2, logits);
    head_kernel<<<512, 256, 0, stream>>>(tokens, logits, tex_W, tex_b, edge_W, edge_b,
                                         str_W, str_b, out, out + 65536, out + 98304,
                                         out + 131072, out + 16941056);
}